// Round 5
// baseline (281.452 us; speedup 1.0000x reference)
//
#include <hip/hip_runtime.h>

// Multi-scale deformable attention, fp32 — level-split version.
// Kernel A: level 0 (2.14 MB/domain, ~0.86 draws/line -> no reuse, stream from L3/HBM).
// Kernel B: levels 1-3 (0.71 MB/domain, 3.4-53x reuse) with XCD swizzle so each
//   XCD's resident working set (~2 domains = 1.6 MB) fits its 4 MiB L2.
// B accumulates into A's output (same stream -> ordered, race-free).
// shapes: bs=8, nq=900, nh=8, d=32, nl=4, npt=4; value: (bs, 22223, nh, d)

#define BS 8
#define NQ 900
#define NH 8
#define NL 4
#define NPT 4
#define NUM_KEYS 22223
#define QC_B 29   // ceil(900/32) q-chunks per (b,h) domain in kernel B

__device__ __forceinline__ float4 bilin_acc(
    const float4* __restrict__ v4, float4 acc,
    unsigned vbase, unsigned rowstride, int H, int W,
    float xn, float yn, float w)
{
    const float xf = xn * (float)W - 0.5f;
    const float yf = yn * (float)H - 0.5f;
    const float fx0 = floorf(xf);
    const float fy0 = floorf(yf);
    const int x0 = (int)fx0;
    const int y0 = (int)fy0;
    float wx1 = xf - fx0, wy1 = yf - fy0;
    float wx0 = 1.f - wx1, wy0 = 1.f - wy1;

    wx0 = (x0 >= 0 && x0 <= W - 1)         ? wx0 : 0.f;
    wx1 = (x0 + 1 >= 0 && x0 + 1 <= W - 1) ? wx1 : 0.f;
    wy0 = (y0 >= 0 && y0 <= H - 1)         ? wy0 : 0.f;
    wy1 = (y0 + 1 >= 0 && y0 + 1 <= H - 1) ? wy1 : 0.f;

    const int x0c = min(max(x0, 0), W - 1);
    const int x1c = min(max(x0 + 1, 0), W - 1);
    const int y0c = min(max(y0, 0), H - 1);
    const int y1c = min(max(y0 + 1, 0), H - 1);

    const unsigned r0 = vbase + (unsigned)y0c * rowstride;
    const unsigned r1 = vbase + (unsigned)y1c * rowstride;

    const float4 v00 = v4[r0 + (unsigned)x0c * (NH * 8)];
    const float4 v01 = v4[r0 + (unsigned)x1c * (NH * 8)];
    const float4 v10 = v4[r1 + (unsigned)x0c * (NH * 8)];
    const float4 v11 = v4[r1 + (unsigned)x1c * (NH * 8)];

    const float s00 = w * wx0 * wy0;
    const float s01 = w * wx1 * wy0;
    const float s10 = w * wx0 * wy1;
    const float s11 = w * wx1 * wy1;

    acc.x = fmaf(s00, v00.x, acc.x); acc.y = fmaf(s00, v00.y, acc.y);
    acc.z = fmaf(s00, v00.z, acc.z); acc.w = fmaf(s00, v00.w, acc.w);
    acc.x = fmaf(s01, v01.x, acc.x); acc.y = fmaf(s01, v01.y, acc.y);
    acc.z = fmaf(s01, v01.z, acc.z); acc.w = fmaf(s01, v01.w, acc.w);
    acc.x = fmaf(s10, v10.x, acc.x); acc.y = fmaf(s10, v10.y, acc.y);
    acc.z = fmaf(s10, v10.z, acc.z); acc.w = fmaf(s10, v10.w, acc.w);
    acc.x = fmaf(s11, v11.x, acc.x); acc.y = fmaf(s11, v11.y, acc.y);
    acc.z = fmaf(s11, v11.z, acc.z); acc.w = fmaf(s11, v11.w, acc.w);
    return acc;
}

// ---------------- Kernel A: level 0, linear dispatch ----------------
__global__ __launch_bounds__(256) void msda_lvl0(
    const float* __restrict__ value,
    const float* __restrict__ loc,
    const float* __restrict__ aw,
    float* __restrict__ out)
{
    const int tid = blockIdx.x * 256 + threadIdx.x;
    const int cg = tid & 7;
    const int h  = (tid >> 3) & 7;
    const int bq = tid >> 6;
    const int b  = bq / NQ;

    const int H = 100, W = 167;
    const float4* __restrict__ v4 = (const float4*)value;
    const unsigned vbase = (unsigned)b * (NUM_KEYS * NH * 8) + h * 8 + cg;
    const unsigned rowstride = (unsigned)W * (NH * 8);

    const int lidx = (bq * NH + h) * NL + 0;
    const float4* __restrict__ loc4 = (const float4*)loc;
    const float4* __restrict__ aw4  = (const float4*)aw;
    const float4 xy01 = loc4[lidx * 2];
    const float4 xy23 = loc4[lidx * 2 + 1];
    const float4 wv   = aw4[lidx];

    float4 acc = {0.f, 0.f, 0.f, 0.f};
    acc = bilin_acc(v4, acc, vbase, rowstride, H, W, xy01.x, xy01.y, wv.x);
    acc = bilin_acc(v4, acc, vbase, rowstride, H, W, xy01.z, xy01.w, wv.y);
    acc = bilin_acc(v4, acc, vbase, rowstride, H, W, xy23.x, xy23.y, wv.z);
    acc = bilin_acc(v4, acc, vbase, rowstride, H, W, xy23.z, xy23.w, wv.w);

    float4* __restrict__ out4 = (float4*)out;
    out4[(bq * NH + h) * 8 + cg] = acc;
}

// ---------------- Kernel B: levels 1-3, XCD-swizzled ----------------
// blockIdx = 8*j + x : XCD slot x (== h), j = b*QC_B + qc (b marches
// sequentially per XCD so each XCD's hot slice stays L2-resident).
__global__ __launch_bounds__(256) void msda_lvl123(
    const float* __restrict__ value,
    const float* __restrict__ loc,
    const float* __restrict__ aw,
    float* __restrict__ out)
{
    const int x  = blockIdx.x & 7;     // XCD slot == h
    const int j  = blockIdx.x >> 3;
    const int b  = j / QC_B;
    const int qc = j - b * QC_B;
    const int h  = x;

    const int cg = threadIdx.x & 7;
    const int qs = threadIdx.x >> 3;   // 0..31
    const int q  = qc * 32 + qs;
    if (q >= NQ) return;

    const float4* __restrict__ v4 = (const float4*)value;
    const unsigned vb0 = (unsigned)b * (NUM_KEYS * NH * 8) + h * 8 + cg;

    const float4* __restrict__ loc4 = (const float4*)loc;
    const float4* __restrict__ aw4  = (const float4*)aw;
    const int lbase = ((b * NQ + q) * NH + h) * NL;

    float4 acc = {0.f, 0.f, 0.f, 0.f};

    const int Hs[3]  = {50, 25, 13};
    const int Ws[3]  = {84, 42, 21};
    const int Sts[3] = {16700, 20900, 21950};

    #pragma unroll
    for (int li = 0; li < 3; ++li) {
        const int H = Hs[li], W = Ws[li];
        const unsigned vbase = vb0 + (unsigned)Sts[li] * (NH * 8);
        const unsigned rowstride = (unsigned)W * (NH * 8);

        const int lidx = lbase + (li + 1);
        const float4 xy01 = loc4[lidx * 2];
        const float4 xy23 = loc4[lidx * 2 + 1];
        const float4 wv   = aw4[lidx];

        acc = bilin_acc(v4, acc, vbase, rowstride, H, W, xy01.x, xy01.y, wv.x);
        acc = bilin_acc(v4, acc, vbase, rowstride, H, W, xy01.z, xy01.w, wv.y);
        acc = bilin_acc(v4, acc, vbase, rowstride, H, W, xy23.x, xy23.y, wv.z);
        acc = bilin_acc(v4, acc, vbase, rowstride, H, W, xy23.z, xy23.w, wv.w);
    }

    float4* __restrict__ out4 = (float4*)out;
    const int oidx = ((b * NQ + q) * NH + h) * 8 + cg;
    const float4 prev = out4[oidx];   // written by kernel A (stream-ordered)
    acc.x += prev.x; acc.y += prev.y; acc.z += prev.z; acc.w += prev.w;
    out4[oidx] = acc;
}

extern "C" void kernel_launch(void* const* d_in, const int* in_sizes, int n_in,
                              void* d_out, int out_size, void* d_ws, size_t ws_size,
                              hipStream_t stream) {
    const float* value = (const float*)d_in[0];
    const float* loc   = (const float*)d_in[1];
    const float* aw    = (const float*)d_in[2];
    float* outp = (float*)d_out;

    // Kernel A: 460800 threads -> 1800 blocks (exact)
    msda_lvl0<<<1800, 256, 0, stream>>>(value, loc, aw, outp);
    // Kernel B: 8 XCD slots * (8 b * 29 qc) = 1856 blocks
    msda_lvl123<<<8 * BS * QC_B, 256, 0, stream>>>(value, loc, aw, outp);
}

// Round 6
// 272.339 us; speedup vs baseline: 1.0335x; 1.0335x over previous
//
#include <hip/hip_runtime.h>
#include <hip/hip_fp16.h>

// Multi-scale deformable attention, fp32 — LDS-staged lvl2+3 version.
// Block = 1024 threads = (b, h, 113-query chunk); 512 blocks total.
// Phase 1: stage lvl2+lvl3 value slice (keys 20900..22222, contiguous,
//          1323 lines x 32ch) into LDS as fp16 (84,672 B).
// Phase 2: thread (q,cg) gathers lvl0/1 from global, lvl2/3 from LDS.
// This converts 236 MB of L3 gather traffic into LDS reads (69 TB/s)
// at the cost of 86 MB of coalesced staging reads.
// blockIdx&7 == h so same-h blocks share an XCD slot if %8 mapping holds.
// shapes: bs=8, nq=900, nh=8, d=32, nl=4, npt=4; value: (bs, 22223, nh, d)

#define BS 8
#define NQ 900
#define NH 8
#define NL 4
#define NUM_KEYS 22223
#define QPB 113           // queries per block: 8 blocks cover 900 (last has 109)
#define ST23 20900        // first key of lvl2 (lvl3 follows contiguously)
#define NLINES 1323       // 25*42 + 13*21
#define LDS_BYTES (NLINES * 32 * 2)   // 84,672 B fp16

// ---- global-memory bilinear accumulate (full fp32) ----
__device__ __forceinline__ float4 bilin_g(
    const float4* __restrict__ v4, float4 acc,
    unsigned vbase, unsigned rowstride, int H, int W,
    float xn, float yn, float w)
{
    const float xf = xn * (float)W - 0.5f;
    const float yf = yn * (float)H - 0.5f;
    const float fx0 = floorf(xf);
    const float fy0 = floorf(yf);
    const int x0 = (int)fx0;
    const int y0 = (int)fy0;
    float wx1 = xf - fx0, wy1 = yf - fy0;
    float wx0 = 1.f - wx1, wy0 = 1.f - wy1;

    wx0 = (x0 >= 0 && x0 <= W - 1)         ? wx0 : 0.f;
    wx1 = (x0 + 1 >= 0 && x0 + 1 <= W - 1) ? wx1 : 0.f;
    wy0 = (y0 >= 0 && y0 <= H - 1)         ? wy0 : 0.f;
    wy1 = (y0 + 1 >= 0 && y0 + 1 <= H - 1) ? wy1 : 0.f;

    const int x0c = min(max(x0, 0), W - 1);
    const int x1c = min(max(x0 + 1, 0), W - 1);
    const int y0c = min(max(y0, 0), H - 1);
    const int y1c = min(max(y0 + 1, 0), H - 1);

    const unsigned r0 = vbase + (unsigned)y0c * rowstride;
    const unsigned r1 = vbase + (unsigned)y1c * rowstride;

    const float4 v00 = v4[r0 + (unsigned)x0c * (NH * 8)];
    const float4 v01 = v4[r0 + (unsigned)x1c * (NH * 8)];
    const float4 v10 = v4[r1 + (unsigned)x0c * (NH * 8)];
    const float4 v11 = v4[r1 + (unsigned)x1c * (NH * 8)];

    const float s00 = w * wx0 * wy0;
    const float s01 = w * wx1 * wy0;
    const float s10 = w * wx0 * wy1;
    const float s11 = w * wx1 * wy1;

    acc.x = fmaf(s00, v00.x, acc.x); acc.y = fmaf(s00, v00.y, acc.y);
    acc.z = fmaf(s00, v00.z, acc.z); acc.w = fmaf(s00, v00.w, acc.w);
    acc.x = fmaf(s01, v01.x, acc.x); acc.y = fmaf(s01, v01.y, acc.y);
    acc.z = fmaf(s01, v01.z, acc.z); acc.w = fmaf(s01, v01.w, acc.w);
    acc.x = fmaf(s10, v10.x, acc.x); acc.y = fmaf(s10, v10.y, acc.y);
    acc.z = fmaf(s10, v10.z, acc.z); acc.w = fmaf(s10, v10.w, acc.w);
    acc.x = fmaf(s11, v11.x, acc.x); acc.y = fmaf(s11, v11.y, acc.y);
    acc.z = fmaf(s11, v11.z, acc.z); acc.w = fmaf(s11, v11.w, acc.w);
    return acc;
}

// ---- LDS (fp16-staged) bilinear accumulate ----
__device__ __forceinline__ float4 bilin_l(
    const __half* __restrict__ lv, float4 acc,
    int lbase, int H, int W, int cg,
    float xn, float yn, float w)
{
    const float xf = xn * (float)W - 0.5f;
    const float yf = yn * (float)H - 0.5f;
    const float fx0 = floorf(xf);
    const float fy0 = floorf(yf);
    const int x0 = (int)fx0;
    const int y0 = (int)fy0;
    float wx1 = xf - fx0, wy1 = yf - fy0;
    float wx0 = 1.f - wx1, wy0 = 1.f - wy1;

    wx0 = (x0 >= 0 && x0 <= W - 1)         ? wx0 : 0.f;
    wx1 = (x0 + 1 >= 0 && x0 + 1 <= W - 1) ? wx1 : 0.f;
    wy0 = (y0 >= 0 && y0 <= H - 1)         ? wy0 : 0.f;
    wy1 = (y0 + 1 >= 0 && y0 + 1 <= H - 1) ? wy1 : 0.f;

    const int x0c = min(max(x0, 0), W - 1);
    const int x1c = min(max(x0 + 1, 0), W - 1);
    const int y0c = min(max(y0, 0), H - 1);
    const int y1c = min(max(y0 + 1, 0), H - 1);

    const int r0 = lbase + y0c * W;
    const int r1 = lbase + y1c * W;

    const __half2* p00 = (const __half2*)(lv + (r0 + x0c) * 32 + cg * 4);
    const __half2* p01 = (const __half2*)(lv + (r0 + x1c) * 32 + cg * 4);
    const __half2* p10 = (const __half2*)(lv + (r1 + x0c) * 32 + cg * 4);
    const __half2* p11 = (const __half2*)(lv + (r1 + x1c) * 32 + cg * 4);

    const float2 a00 = __half22float2(p00[0]), b00 = __half22float2(p00[1]);
    const float2 a01 = __half22float2(p01[0]), b01 = __half22float2(p01[1]);
    const float2 a10 = __half22float2(p10[0]), b10 = __half22float2(p10[1]);
    const float2 a11 = __half22float2(p11[0]), b11 = __half22float2(p11[1]);

    const float s00 = w * wx0 * wy0;
    const float s01 = w * wx1 * wy0;
    const float s10 = w * wx0 * wy1;
    const float s11 = w * wx1 * wy1;

    acc.x = fmaf(s00, a00.x, acc.x); acc.y = fmaf(s00, a00.y, acc.y);
    acc.z = fmaf(s00, b00.x, acc.z); acc.w = fmaf(s00, b00.y, acc.w);
    acc.x = fmaf(s01, a01.x, acc.x); acc.y = fmaf(s01, a01.y, acc.y);
    acc.z = fmaf(s01, b01.x, acc.z); acc.w = fmaf(s01, b01.y, acc.w);
    acc.x = fmaf(s10, a10.x, acc.x); acc.y = fmaf(s10, a10.y, acc.y);
    acc.z = fmaf(s10, b10.x, acc.z); acc.w = fmaf(s10, b10.y, acc.w);
    acc.x = fmaf(s11, a11.x, acc.x); acc.y = fmaf(s11, a11.y, acc.y);
    acc.z = fmaf(s11, b11.x, acc.z); acc.w = fmaf(s11, b11.y, acc.w);
    return acc;
}

__global__ __launch_bounds__(1024, 1) void msda_kernel(
    const float* __restrict__ value,
    const float* __restrict__ loc,
    const float* __restrict__ aw,
    float* __restrict__ out)
{
    extern __shared__ __half lv[];   // NLINES*32 fp16 = 84,672 B

    // blockIdx = qb*64 + bh  ->  blockIdx&7 == h (XCD-slot affinity on h)
    const int bh = blockIdx.x & 63;
    const int qb = blockIdx.x >> 6;   // 0..7
    const int b  = bh >> 3;
    const int h  = bh & 7;

    const float4* __restrict__ v4 = (const float4*)value;

    // ---- Phase 1: stage lvl2+lvl3 slice into LDS as fp16 ----
    // float4 i covers (key = ST23 + i/8, sub = i%8); coalesced 128 B per 8 lanes.
    const unsigned sbase = (unsigned)(b * NUM_KEYS + ST23) * (NH * 8) + h * 8;
    for (int i = threadIdx.x; i < NLINES * 8; i += 1024) {
        const int key = i >> 3;
        const int sub = i & 7;
        const float4 v = v4[sbase + (unsigned)key * (NH * 8) + sub];
        __half2* dst = (__half2*)(lv + i * 4);
        dst[0] = __floats2half2_rn(v.x, v.y);
        dst[1] = __floats2half2_rn(v.z, v.w);
    }
    __syncthreads();

    // ---- Phase 2: compute ----
    const int cg = threadIdx.x & 7;      // channel group (4 floats)
    const int tq = threadIdx.x >> 3;     // 0..127
    const int q0 = qb * QPB;
    const int qcount = min(NQ - q0, QPB);
    if (tq >= qcount) return;            // no barriers after this point
    const int q = q0 + tq;

    const unsigned vb0 = (unsigned)b * (NUM_KEYS * NH * 8) + h * 8 + cg;

    const float4* __restrict__ loc4 = (const float4*)loc;
    const float4* __restrict__ aw4  = (const float4*)aw;
    const int lbase = ((b * NQ + q) * NH + h) * NL;

    float4 acc = {0.f, 0.f, 0.f, 0.f};

    // lvl0: H=100 W=167 St=0 (global)
    {
        const float4 xy01 = loc4[(lbase + 0) * 2];
        const float4 xy23 = loc4[(lbase + 0) * 2 + 1];
        const float4 wv   = aw4[lbase + 0];
        const unsigned rs = 167u * (NH * 8);
        acc = bilin_g(v4, acc, vb0, rs, 100, 167, xy01.x, xy01.y, wv.x);
        acc = bilin_g(v4, acc, vb0, rs, 100, 167, xy01.z, xy01.w, wv.y);
        acc = bilin_g(v4, acc, vb0, rs, 100, 167, xy23.x, xy23.y, wv.z);
        acc = bilin_g(v4, acc, vb0, rs, 100, 167, xy23.z, xy23.w, wv.w);
    }
    // lvl1: H=50 W=84 St=16700 (global)
    {
        const float4 xy01 = loc4[(lbase + 1) * 2];
        const float4 xy23 = loc4[(lbase + 1) * 2 + 1];
        const float4 wv   = aw4[lbase + 1];
        const unsigned vb1 = vb0 + 16700u * (NH * 8);
        const unsigned rs = 84u * (NH * 8);
        acc = bilin_g(v4, acc, vb1, rs, 50, 84, xy01.x, xy01.y, wv.x);
        acc = bilin_g(v4, acc, vb1, rs, 50, 84, xy01.z, xy01.w, wv.y);
        acc = bilin_g(v4, acc, vb1, rs, 50, 84, xy23.x, xy23.y, wv.z);
        acc = bilin_g(v4, acc, vb1, rs, 50, 84, xy23.z, xy23.w, wv.w);
    }
    // lvl2: H=25 W=42 (LDS, line base 0)
    {
        const float4 xy01 = loc4[(lbase + 2) * 2];
        const float4 xy23 = loc4[(lbase + 2) * 2 + 1];
        const float4 wv   = aw4[lbase + 2];
        acc = bilin_l(lv, acc, 0, 25, 42, cg, xy01.x, xy01.y, wv.x);
        acc = bilin_l(lv, acc, 0, 25, 42, cg, xy01.z, xy01.w, wv.y);
        acc = bilin_l(lv, acc, 0, 25, 42, cg, xy23.x, xy23.y, wv.z);
        acc = bilin_l(lv, acc, 0, 25, 42, cg, xy23.z, xy23.w, wv.w);
    }
    // lvl3: H=13 W=21 (LDS, line base 1050)
    {
        const float4 xy01 = loc4[(lbase + 3) * 2];
        const float4 xy23 = loc4[(lbase + 3) * 2 + 1];
        const float4 wv   = aw4[lbase + 3];
        acc = bilin_l(lv, acc, 1050, 13, 21, cg, xy01.x, xy01.y, wv.x);
        acc = bilin_l(lv, acc, 1050, 13, 21, cg, xy01.z, xy01.w, wv.y);
        acc = bilin_l(lv, acc, 1050, 13, 21, cg, xy23.x, xy23.y, wv.z);
        acc = bilin_l(lv, acc, 1050, 13, 21, cg, xy23.z, xy23.w, wv.w);
    }

    float4* __restrict__ out4 = (float4*)out;
    out4[((b * NQ + q) * NH + h) * 8 + cg] = acc;
}

extern "C" void kernel_launch(void* const* d_in, const int* in_sizes, int n_in,
                              void* d_out, int out_size, void* d_ws, size_t ws_size,
                              hipStream_t stream) {
    const float* value = (const float*)d_in[0];
    const float* loc   = (const float*)d_in[1];
    const float* aw    = (const float*)d_in[2];
    float* outp = (float*)d_out;

    // 8 q-chunks x 64 (b,h) domains = 512 blocks of 1024 threads
    msda_kernel<<<512, 1024, LDS_BYTES, stream>>>(value, loc, aw, outp);
}